// Round 9
// baseline (4847.429 us; speedup 1.0000x reference)
//
#include <hip/hip_runtime.h>
#include <hip/hip_bf16.h>
#include <math.h>

// GGNN: L=5 layers of { m = h@W_l ; agg = scatter_add(ew * m[src] -> dst) ;
//                       h = GRUCell(agg, h) } then out = relu(h)@fc_w^T + fc_b
// H=256, N=50000, E=800000.
//
// R8 lesson: traffic fix (FETCH 344->86MB) didn't move the ~412us gates
// floor; all pipes <15% busy at 10 waves/CU. R9: 512-thread blocks (8 waves),
// 128-row x 64-col tiles, same per-wave fragment shape. Weight staging per
// block unchanged -> per-row cost halves; LDS stays 48KB -> 3 blocks/CU =
// 24 waves/CU (2.4x) to cover the per-chunk barrier drains.

#define HDIM 256

using bf16x8 = __attribute__((ext_vector_type(8))) short;
using f32x4  = __attribute__((ext_vector_type(4))) float;

__device__ __forceinline__ bf16x8 ldfrag(const ushort* p) {
    union { uint4 u; bf16x8 f; } x;
    x.u = *(const uint4*)p;
    return x.f;
}
#define MFMA(a, b, c) __builtin_amdgcn_mfma_f32_16x16x32_bf16((a), (b), (c), 0, 0, 0)
// async global->LDS, 16B per lane; LDS dest = wave-uniform base + lane*16
#define GLD16(g, l)                                                            \
    __builtin_amdgcn_global_load_lds(                                          \
        (const __attribute__((address_space(1))) void*)(g),                    \
        (__attribute__((address_space(3))) void*)(l), 16, 0, 0)

__device__ __forceinline__ float ldf(const void* p, size_t i, int isbf) {
    if (isbf) return __bfloat162float(((const __hip_bfloat16*)p)[i]);
    return ((const float*)p)[i];
}
__device__ __forceinline__ ushort f2bs(float v) {
    __hip_bfloat16 b = __float2bfloat16(v);
    return *(ushort*)&b;
}
__device__ __forceinline__ float bs2f(ushort u) {
    __hip_bfloat16 b = *(__hip_bfloat16*)&u;
    return __bfloat162float(b);
}
// MFMA-tile layout address (elements) for plane element (n, k)
__device__ __forceinline__ size_t taddr(int n, int k) {
    return (size_t)(n >> 4) * 4096 + (size_t)((k >> 5) << 9)
         + (size_t)(((k >> 3) & 3) << 7) + (size_t)((n & 15) << 3) + (k & 7);
}

// flags[0] = 1 if float tensors are bf16, 0 if f32
// flags[1] = 1 if edge_index is int64, 0 if int32
__global__ void detect_k(const void* x, const void* ei, int* flags) {
    if (blockIdx.x == 0 && threadIdx.x == 0) {
        const __hip_bfloat16* xb = (const __hip_bfloat16*)x;
        int isbf = 1;
        for (int i = 0; i < 1024; ++i) {
            float v = fabsf(__bfloat162float(xb[i]));
            if (!(v < 1e6f)) { isbf = 0; break; }
        }
        flags[0] = isbf;
        const int* e32 = (const int*)ei;
        int orv = e32[1] | e32[3] | e32[5] | e32[7] | e32[9] | e32[11];
        flags[1] = (orv == 0) ? 1 : 0;
    }
}

// x -> h hi/lo planes (tiled layout); pad rows (n>=Nn) zeroed every call
__global__ void conv_h0_k(const void* x, ushort* hH, ushort* hL,
                          const int* flags, int Nn, size_t nhp) {
    size_t i = (size_t)blockIdx.x * blockDim.x + threadIdx.x;
    if (i >= nhp) return;
    const int n = (int)(i >> 8), k = (int)(i & 255);
    float v = 0.f;
    if (n < Nn) v = ldf(x, i, flags[0]);
    const ushort h = f2bs(v);
    const size_t a = taddr(n, k);
    hH[a] = h;
    hL[a] = f2bs(v - bs2f(h));
}

// Weight planes (row-major, NT form). Wt[l][j][k] = weight[l][k][j].
// Wih/Whh direct [768][256] copies (gate order r,z,n). Split hi/lo. Biases f32.
__global__ void prep_k(const void* w, const void* wih, const void* whh,
                       const void* bih, const void* bhh,
                       ushort* WtH, ushort* WtL, ushort* WihH, ushort* WihL,
                       ushort* WhhH, ushort* WhhL,
                       float* bsum, float* bni, float* bnh,
                       const int* flags, int L) {
    int i = blockIdx.x * blockDim.x + threadIdx.x;
    int isbf = flags[0];
    if (i < L * 65536) {
        int l = i >> 16, rem = i & 65535;
        int j = rem >> 8, k = rem & 255;
        float v = ldf(w, ((size_t)l << 16) + (size_t)k * 256 + j, isbf);
        ushort h = f2bs(v);
        WtH[i] = h; WtL[i] = f2bs(v - bs2f(h));
    }
    if (i < 196608) {
        float a = ldf(wih, i, isbf);
        ushort ah = f2bs(a);
        WihH[i] = ah; WihL[i] = f2bs(a - bs2f(ah));
        float b = ldf(whh, i, isbf);
        ushort bh = f2bs(b);
        WhhH[i] = bh; WhhL[i] = f2bs(b - bs2f(bh));
    }
    if (i < 512) bsum[i] = ldf(bih, i, isbf) + ldf(bhh, i, isbf);
    if (i < 256) {
        bni[i] = ldf(bih, 512 + i, isbf);
        bnh[i] = ldf(bhh, 512 + i, isbf);
    }
}

// ---------------- CSR build (by dst), once per call ----------------

__global__ void zero_int_k(int* p, int n) {
    int i = blockIdx.x * blockDim.x + threadIdx.x;
    if (i < n) p[i] = 0;
}

__global__ void count_k(const void* ei, int* cnt, const int* flags, int E) {
    int e = blockIdx.x * blockDim.x + threadIdx.x;
    if (e >= E) return;
    const int* e32 = (const int*)ei;
    int d = flags[1] ? e32[2 * ((size_t)E + e)] : e32[(size_t)E + e];
    atomicAdd(&cnt[d], 1);
}

__global__ __launch_bounds__(256)
void scan1_k(const int* cnt, int* ptr, int* bsumN, int N) {
    __shared__ int s[256];
    const int t = threadIdx.x;
    const int gid = blockIdx.x * 256 + t;
    int v = (gid < N) ? cnt[gid] : 0;
    const int own = v;
    s[t] = v;
    __syncthreads();
#pragma unroll
    for (int off = 1; off < 256; off <<= 1) {
        int add = (t >= off) ? s[t - off] : 0;
        __syncthreads();
        s[t] += add;
        __syncthreads();
    }
    if (gid < N) ptr[gid] = s[t] - own;
    if (t == 255) bsumN[blockIdx.x] = s[255];
}

__global__ __launch_bounds__(256)
void scan2_k(int* bsumN, int NB) {
    __shared__ int s[256];
    __shared__ int carry;
    const int t = threadIdx.x;
    if (t == 0) carry = 0;
    __syncthreads();
    for (int base = 0; base < NB; base += 256) {
        const int i = base + t;
        int v = (i < NB) ? bsumN[i] : 0;
        const int own = v;
        s[t] = v;
        __syncthreads();
#pragma unroll
        for (int off = 1; off < 256; off <<= 1) {
            int add = (t >= off) ? s[t - off] : 0;
            __syncthreads();
            s[t] += add;
            __syncthreads();
        }
        if (i < NB) bsumN[i] = carry + s[t] - own;
        __syncthreads();
        if (t == 0) carry += s[255];
        __syncthreads();
    }
}

__global__ void scan3_k(int* ptr, int* cursor, const int* bsumN, int N, int E) {
    const int gid = blockIdx.x * 256 + threadIdx.x;
    if (gid < N) {
        const int p = ptr[gid] + bsumN[blockIdx.x];
        ptr[gid] = p;
        cursor[gid] = p;
    }
    if (gid == 0) ptr[N] = E;
}

__global__ void fill_k(const void* ei, const void* ew, int* cursor,
                       int* srcs, float* wse, const int* flags, int E) {
    int e = blockIdx.x * blockDim.x + threadIdx.x;
    if (e >= E) return;
    const int* e32 = (const int*)ei;
    int s, d;
    if (flags[1]) { s = e32[2 * (size_t)e]; d = e32[2 * ((size_t)E + e)]; }
    else          { s = e32[e];             d = e32[(size_t)E + e]; }
    const int p = atomicAdd(&cursor[d], 1);
    srcs[p] = s;
    wse[p] = ldf(ew, e, flags[0]);
}

// ---------------- SpMM gather: agg[d] = sum_j w_j * m[src_j] ----------------
// agg written in tiled-plane layout.
__global__ __launch_bounds__(256)
void spmm_k(const float* __restrict__ m, const int* __restrict__ ptr,
            const int* __restrict__ srcs, const float* __restrict__ wse,
            ushort* __restrict__ aggH, ushort* __restrict__ aggL, int N) {
    const int node = blockIdx.x * 4 + (threadIdx.x >> 6);
    if (node >= N) return;
    const int lane4 = (threadIdx.x & 63) << 2;
    const int p0 = ptr[node], p1 = ptr[node + 1];
    float4 acc = make_float4(0.f, 0.f, 0.f, 0.f);
    int j = p0;
    for (; j + 1 < p1; j += 2) {
        const int s0 = srcs[j], s1 = srcs[j + 1];
        const float w0 = wse[j], w1 = wse[j + 1];
        const float4 v0 = *(const float4*)&m[(size_t)s0 * HDIM + lane4];
        const float4 v1 = *(const float4*)&m[(size_t)s1 * HDIM + lane4];
        acc.x = fmaf(w0, v0.x, acc.x); acc.y = fmaf(w0, v0.y, acc.y);
        acc.z = fmaf(w0, v0.z, acc.z); acc.w = fmaf(w0, v0.w, acc.w);
        acc.x = fmaf(w1, v1.x, acc.x); acc.y = fmaf(w1, v1.y, acc.y);
        acc.z = fmaf(w1, v1.z, acc.z); acc.w = fmaf(w1, v1.w, acc.w);
    }
    if (j < p1) {
        const int s0 = srcs[j];
        const float w0 = wse[j];
        const float4 v0 = *(const float4*)&m[(size_t)s0 * HDIM + lane4];
        acc.x = fmaf(w0, v0.x, acc.x); acc.y = fmaf(w0, v0.y, acc.y);
        acc.z = fmaf(w0, v0.z, acc.z); acc.w = fmaf(w0, v0.w, acc.w);
    }
    ushort4 hi, lo;
    hi.x = f2bs(acc.x); lo.x = f2bs(acc.x - bs2f(hi.x));
    hi.y = f2bs(acc.y); lo.y = f2bs(acc.y - bs2f(hi.y));
    hi.z = f2bs(acc.z); lo.z = f2bs(acc.z - bs2f(hi.z));
    hi.w = f2bs(acc.w); lo.w = f2bs(acc.w - bs2f(hi.w));
    const size_t a = taddr(node, lane4);
    *(ushort4*)&aggH[a] = hi;
    *(ushort4*)&aggL[a] = lo;
}

// ---------------- MFMA GEMMs: 8 waves, 128x64 tiles -------------------------
// Block: 512 threads = 8 waves; tile 128 rows x 64 cols; K-chunks of 32.
// Wave w handles rows r0 + w*16 .. +15 (A tiles rb*8+w). Weight tile in LDS
// (per strip [64 cols][32 halves], staged once per block per chunk via glds,
// conflict-free: reads at s*2048 + cb*512 + lq*128 + lm*8 = free 2-way).
// Double-buffered weights + register A prefetch; 1 barrier per chunk.
// XCD swizzle: bid=((rhi*4+cg)<<3)|rlo co-schedules 4 col-group peers.
// C/D: col = lane&15, row = (lane>>4)*4 + reg.

// m = h @ Wt^T (m stays f32 row-major for spmm)
__global__ __launch_bounds__(512, 6)
void mfma_gemm1_k(const ushort* __restrict__ hH, const ushort* __restrict__ hL,
                  const ushort* __restrict__ WH, const ushort* __restrict__ WL,
                  float* __restrict__ m, const int* __restrict__ flags,
                  int N, int gmB) {
    __shared__ ushort smW[2 * 2048];  // 8 KB: [buf][64 cols][32 halves]
    const int bid = blockIdx.x;
    const int rlo = bid & 7, q = bid >> 3;
    const int cg = q & 3, rhi = q >> 2;
    const int rb = rhi * 8 + rlo;
    if (rb >= gmB) return;
    const int tid = threadIdx.x;
    const int lane = tid & 63;
    const int wvu = __builtin_amdgcn_readfirstlane(tid >> 6);  // 0..7
    const int r0 = rb * 128, c0 = cg * 64;
    const int lm = lane & 15, lq = lane >> 4;
    const int fullsplit = !flags[0];
    const size_t wgbase = (size_t)(c0 + (wvu & 3) * 16 + lm) * 256 + lq * 8;
    const size_t abase = (size_t)(rb * 8 + wvu) * 4096 + lane * 8;
    f32x4 acc[4];
#pragma unroll
    for (int cb = 0; cb < 4; ++cb) acc[cb] = (f32x4){0.f, 0.f, 0.f, 0.f};

    if (wvu < 4) GLD16(WH + wgbase, &smW[wvu * 512]);
    bf16x8 c_ah = ldfrag(hH + abase);
    bf16x8 c_al = ldfrag(hL + abase);
    for (int c = 0; c < 8; ++c) {
        const int ks = c * 32;
        __syncthreads();  // drains loads issued one compute-phase ago
        bf16x8 n_ah, n_al;
        if (c < 7) {
            if (wvu < 4)
                GLD16(WH + wgbase + ks + 32, &smW[((c + 1) & 1) * 2048 + wvu * 512]);
            const size_t ao = abase + (size_t)(c + 1) * 512;
            n_ah = ldfrag(hH + ao);
            n_al = ldfrag(hL + ao);
        }
        const ushort* wb0 = &smW[(c & 1) * 2048];
#pragma unroll
        for (int cb = 0; cb < 4; ++cb) {
            const bf16x8 w = ldfrag(&wb0[cb * 512 + lq * 128 + lm * 8]);
            acc[cb] = MFMA(c_ah, w, acc[cb]);
            acc[cb] = MFMA(c_al, w, acc[cb]);
            if (fullsplit) {
                const bf16x8 wl = ldfrag(&WL[(size_t)(c0 + cb * 16 + lm) * 256 + ks + lq * 8]);
                acc[cb] = MFMA(c_ah, wl, acc[cb]);
            }
        }
        if (c < 7) { c_ah = n_ah; c_al = n_al; }
    }
#pragma unroll
    for (int cb = 0; cb < 4; ++cb) {
        const int col = c0 + cb * 16 + lm;
#pragma unroll
        for (int v = 0; v < 4; ++v) {
            const int row = r0 + wvu * 16 + lq * 4 + v;
            if (row < N) m[(size_t)row * 256 + col] = acc[cb][v];
        }
    }
}

// Fused GRU gates + update. 8 waves, 128x64 tile; 6 weight strips dbuf via
// glds (48 KB LDS; wave w stages strips 3*(w>>2).. at col-quarter w&3);
// A planes prefetched global->register; epilogue sigmoid/tanh/mix.
__global__ __launch_bounds__(512, 6)
void mfma_gates_k(const ushort* __restrict__ agH, const ushort* __restrict__ agL,
                  const ushort* __restrict__ hoH, const ushort* __restrict__ hoL,
                  const ushort* __restrict__ WihH, const ushort* __restrict__ WihL,
                  const ushort* __restrict__ WhhH, const ushort* __restrict__ WhhL,
                  const float* __restrict__ bsum, const float* __restrict__ bni,
                  const float* __restrict__ bnh,
                  ushort* __restrict__ hnH, ushort* __restrict__ hnL,
                  const int* __restrict__ flags, int N, int gmB) {
    __shared__ ushort smW[2 * 6 * 2048];  // 48 KB
    const int bid = blockIdx.x;
    const int rlo = bid & 7, q = bid >> 3;
    const int cg = q & 3, rhi = q >> 2;
    const int rb = rhi * 8 + rlo;
    if (rb >= gmB) return;
    const int tid = threadIdx.x;
    const int lane = tid & 63;
    const int wvu = __builtin_amdgcn_readfirstlane(tid >> 6);  // 0..7
    const int r0 = rb * 128, c0 = cg * 64;
    const int lm = lane & 15, lq = lane >> 4;
    const int fullsplit = !flags[0];
    const int colq = wvu & 3, sg = (wvu >> 2) * 3;
    const size_t wgbase = (size_t)(c0 + colq * 16 + lm) * 256 + lq * 8;
    const size_t abase = (size_t)(rb * 8 + wvu) * 4096 + lane * 8;
    f32x4 aR[4], aZ[4], aNI[4], aNH[4];
#pragma unroll
    for (int cb = 0; cb < 4; ++cb) {
        aR[cb] = (f32x4){0.f, 0.f, 0.f, 0.f};
        aZ[cb] = (f32x4){0.f, 0.f, 0.f, 0.f};
        aNI[cb] = (f32x4){0.f, 0.f, 0.f, 0.f};
        aNH[cb] = (f32x4){0.f, 0.f, 0.f, 0.f};
    }

    const ushort* Wsrc[6] = {WihH, WihH + 65536, WihH + 131072,
                             WhhH, WhhH + 65536, WhhH + 131072};
#pragma unroll
    for (int j = 0; j < 3; ++j)
        GLD16(Wsrc[sg + j] + wgbase, &smW[(sg + j) * 2048 + colq * 512]);
    bf16x8 c_ah = ldfrag(agH + abase);
    bf16x8 c_al = ldfrag(agL + abase);
    bf16x8 c_hh = ldfrag(hoH + abase);
    bf16x8 c_hl = ldfrag(hoL + abase);
    for (int c = 0; c < 8; ++c) {
        const int ks = c * 32;
        __syncthreads();
        bf16x8 n_ah, n_al, n_hh, n_hl;
        if (c < 7) {
            const int nb = (c + 1) & 1;
#pragma unroll
            for (int j = 0; j < 3; ++j)
                GLD16(Wsrc[sg + j] + wgbase + ks + 32,
                      &smW[nb * 12288 + (sg + j) * 2048 + colq * 512]);
            const size_t ao = abase + (size_t)(c + 1) * 512;
            n_ah = ldfrag(agH + ao);
            n_al = ldfrag(agL + ao);
            n_hh = ldfrag(hoH + ao);
            n_hl = ldfrag(hoL + ao);
        }
        const ushort* wb0 = &smW[(c & 1) * 12288];
#pragma unroll
        for (int cb = 0; cb < 4; ++cb) {
            const int wb = cb * 512 + lq * 128 + lm * 8;
            const bf16x8 wri = ldfrag(&wb0[0 * 2048 + wb]);
            const bf16x8 wzi = ldfrag(&wb0[1 * 2048 + wb]);
            const bf16x8 wni = ldfrag(&wb0[2 * 2048 + wb]);
            const bf16x8 wrh = ldfrag(&wb0[3 * 2048 + wb]);
            const bf16x8 wzh = ldfrag(&wb0[4 * 2048 + wb]);
            const bf16x8 wnh = ldfrag(&wb0[5 * 2048 + wb]);
            aR[cb] = MFMA(c_ah, wri, aR[cb]);
            aZ[cb] = MFMA(c_ah, wzi, aZ[cb]);
            aNI[cb] = MFMA(c_ah, wni, aNI[cb]);
            aNH[cb] = MFMA(c_hh, wnh, aNH[cb]);
            aR[cb] = MFMA(c_al, wri, aR[cb]);
            aZ[cb] = MFMA(c_al, wzi, aZ[cb]);
            aNI[cb] = MFMA(c_al, wni, aNI[cb]);
            aNH[cb] = MFMA(c_hl, wnh, aNH[cb]);
            aR[cb] = MFMA(c_hh, wrh, aR[cb]);
            aZ[cb] = MFMA(c_hh, wzh, aZ[cb]);
            aR[cb] = MFMA(c_hl, wrh, aR[cb]);
            aZ[cb] = MFMA(c_hl, wzh, aZ[cb]);
            if (fullsplit) {
                const size_t wr = (size_t)(c0 + cb * 16 + lm) * 256 + ks + lq * 8;
                aR[cb] = MFMA(c_ah, ldfrag(WihL + wr), aR[cb]);
                aR[cb] = MFMA(c_hh, ldfrag(WhhL + wr), aR[cb]);
                aZ[cb] = MFMA(c_ah, ldfrag(WihL + wr + 65536), aZ[cb]);
                aZ[cb] = MFMA(c_hh, ldfrag(WhhL + wr + 65536), aZ[cb]);
                aNI[cb] = MFMA(c_ah, ldfrag(WihL + wr + 131072), aNI[cb]);
                aNH[cb] = MFMA(c_hh, ldfrag(WhhL + wr + 131072), aNH[cb]);
            }
        }
        if (c < 7) { c_ah = n_ah; c_al = n_al; c_hh = n_hh; c_hl = n_hl; }
    }
#pragma unroll
    for (int cb = 0; cb < 4; ++cb) {
        const int col = c0 + cb * 16 + lm;
        const float rb_ = bsum[col];
        const float zb = bsum[256 + col];
        const float ib = bni[col];
        const float hb = bnh[col];
#pragma unroll
        for (int v = 0; v < 4; ++v) {
            const int row = r0 + wvu * 16 + lq * 4 + v;
            if (row < N) {
                const size_t off = taddr(row, col);
                const float hold = bs2f(hoH[off]) + bs2f(hoL[off]);
                const float r = 1.f / (1.f + expf(-(aR[cb][v] + rb_)));
                const float z = 1.f / (1.f + expf(-(aZ[cb][v] + zb)));
                const float nn = tanhf(aNI[cb][v] + ib + r * (aNH[cb][v] + hb));
                const float hv = (1.f - z) * nn + z * hold;
                const ushort hi = f2bs(hv);
                hnH[off] = hi;
                hnL[off] = f2bs(hv - bs2f(hi));
            }
        }
    }
}

// out[n] = sum_t relu(h[n,t]) * fc_w[t] + fc_b ; one 256-thread block per node
__global__ void final_k(const ushort* __restrict__ hH, const ushort* __restrict__ hL,
                        const void* fcw, const void* fcb,
                        void* out, const int* flags, int N) {
    const int n = blockIdx.x;
    const int t = threadIdx.x;
    const int isbf = flags[0];
    const size_t off = taddr(n, t);
    float v = fmaxf(bs2f(hH[off]) + bs2f(hL[off]), 0.f) * ldf(fcw, t, isbf);
#pragma unroll
    for (int offx = 32; offx >= 1; offx >>= 1) v += __shfl_down(v, offx);
    __shared__ float red[4];
    if ((t & 63) == 0) red[t >> 6] = v;
    __syncthreads();
    if (t == 0) {
        const float s = red[0] + red[1] + red[2] + red[3] + ldf(fcb, 0, isbf);
        if (isbf) ((__hip_bfloat16*)out)[n] = __float2bfloat16(s);
        else      ((float*)out)[n] = s;
    }
}

extern "C" void kernel_launch(void* const* d_in, const int* in_sizes, int n_in,
                              void* d_out, int out_size, void* d_ws, size_t ws_size,
                              hipStream_t stream) {
    const int H = HDIM;
    const int N = in_sizes[0] / H;       // 50000
    const int E = in_sizes[2];           // 800000
    const int L = in_sizes[3] / (H * H); // 5
    const size_t NH = (size_t)N * H;
    const int NB = (N + 255) / 256;
    const int gmB = (N + 127) / 128;     // 391 row-blocks (128 rows each)
    const int gmp = ((gmB + 7) / 8) * 8; // 392 (pad for swizzle decode)
    const size_t NHP = (size_t)((N + 63) / 64) * 64 * 256;  // padded plane (50048*256)

    char* base = (char*)d_ws;
    int*  flags = (int*)base;                         // 64 B
    char* regA  = base + 64;                          // NHP*4 B (h planes / m)
    char* regB  = regA + NHP * 4;                     // NHP*4 B
    ushort* aggH = (ushort*)(regB + NHP * 4);         // NHP
    ushort* aggL = aggH + NHP;                        // NHP
    ushort* WtH  = aggL + NHP;                        // L*65536
    ushort* WtL  = WtH + (size_t)L * 65536;
    ushort* WihH = WtL + (size_t)L * 65536;           // 196608
    ushort* WihL = WihH + 196608;
    ushort* WhhH = WihL + 196608;
    ushort* WhhL = WhhH + 196608;
    float* bsum  = (float*)(WhhL + 196608);           // 512
    float* bni   = bsum + 512;                        // 256
    float* bnh   = bni + 256;                         // 256
    int* ptr     = (int*)(bnh + 256);                 // N+1
    int* cursor  = ptr + (N + 1);                     // N
    int* bsumN   = cursor + N;                        // NB
    int* srcs    = bsumN + NB;                        // E
    float* wse   = (float*)(srcs + E);                // E
    // total ~= 166 MiB

    detect_k<<<dim3(1), dim3(64), 0, stream>>>(d_in[0], d_in[1], flags);
    conv_h0_k<<<dim3((unsigned)((NHP + 255) / 256)), dim3(256), 0, stream>>>(
        d_in[0], (ushort*)regA, (ushort*)regA + NHP, flags, N, NHP);
    prep_k<<<dim3((L * 65536 + 255) / 256), dim3(256), 0, stream>>>(
        d_in[3], d_in[4], d_in[5], d_in[6], d_in[7],
        WtH, WtL, WihH, WihL, WhhH, WhhL, bsum, bni, bnh, flags, L);

    zero_int_k<<<dim3(NB), dim3(256), 0, stream>>>(cursor, N);
    count_k<<<dim3((E + 255) / 256), dim3(256), 0, stream>>>(d_in[1], cursor, flags, E);
    scan1_k<<<dim3(NB), dim3(256), 0, stream>>>(cursor, ptr, bsumN, N);
    scan2_k<<<dim3(1), dim3(256), 0, stream>>>(bsumN, NB);
    scan3_k<<<dim3(NB), dim3(256), 0, stream>>>(ptr, cursor, bsumN, N, E);
    fill_k<<<dim3((E + 255) / 256), dim3(256), 0, stream>>>(
        d_in[1], d_in[2], cursor, srcs, wse, flags, E);

    const dim3 blk(256);
    const dim3 blk512(512);
    const unsigned grid2 = (unsigned)(4 * gmp);
    char* regH = regA;  // current h (hi/lo planes)
    char* regM = regB;  // m (f32), later h_new planes
    for (int l = 0; l < L; ++l) {
        ushort* hH = (ushort*)regH;
        ushort* hL = hH + NHP;
        mfma_gemm1_k<<<dim3(grid2), blk512, 0, stream>>>(
            hH, hL, WtH + (size_t)l * 65536, WtL + (size_t)l * 65536,
            (float*)regM, flags, N, gmB);
        spmm_k<<<dim3((N + 3) / 4), blk, 0, stream>>>(
            (const float*)regM, ptr, srcs, wse, aggH, aggL, N);
        mfma_gates_k<<<dim3(grid2), blk512, 0, stream>>>(
            aggH, aggL, hH, hL, WihH, WihL, WhhH, WhhL, bsum, bni, bnh,
            (ushort*)regM, (ushort*)regM + NHP, flags, N, gmB);
        char* t = regH; regH = regM; regM = t;
    }
    final_k<<<dim3(N), blk, 0, stream>>>(
        (ushort*)regH, (ushort*)regH + NHP, d_in[8], d_in[9], d_out, flags, N);
}

// Round 10
// 2298.839 us; speedup vs baseline: 2.1086x; 2.1086x over previous
//
#include <hip/hip_runtime.h>
#include <hip/hip_bf16.h>
#include <math.h>

// GGNN: L=5 layers of { m = h@W_l ; agg = scatter_add(ew * m[src] -> dst) ;
//                       h = GRUCell(agg, h) } then out = relu(h)@fc_w^T + fc_b
// H=256, N=50000, E=800000.
//
// R9 lesson: __launch_bounds__(512,6) register-capped -> acc spills (FETCH
// 821MB). R5-R8 lesson: 64x64/16-acc structure pinned at ~190 TF regardless
// of conflicts/traffic/occupancy. R10: m97-faithful GEMM (128x128 tile,
// 4 waves x 4x4 16x16-tiles = 64 acc/thread, BK=32, glds-staged A+B tiles,
// 2 barriers/chunk). Gates GEMM densified: A = [aggH|aggL|hH(|hL)] via
// chunk-uniform base select; B = prep-built permuted matrix with output cols
// interleaved [r|z|ni|nh] per 64 so the GRU epilogue is wave-local.
// h hi/lo planes only if ws_size allows (host-side check, graph-safe).

#define HDIM 256

using bf16x8 = __attribute__((ext_vector_type(8))) short;
using f32x4  = __attribute__((ext_vector_type(4))) float;

__device__ __forceinline__ bf16x8 ldfrag(const ushort* p) {
    union { uint4 u; bf16x8 f; } x;
    x.u = *(const uint4*)p;
    return x.f;
}
#define MFMA(a, b, c) __builtin_amdgcn_mfma_f32_16x16x32_bf16((a), (b), (c), 0, 0, 0)
#define GLD16(g, l)                                                            \
    __builtin_amdgcn_global_load_lds(                                          \
        (const __attribute__((address_space(1))) void*)(g),                    \
        (__attribute__((address_space(3))) void*)(l), 16, 0, 0)

__device__ __forceinline__ float ldf(const void* p, size_t i, int isbf) {
    if (isbf) return __bfloat162float(((const __hip_bfloat16*)p)[i]);
    return ((const float*)p)[i];
}
__device__ __forceinline__ ushort f2bs(float v) {
    __hip_bfloat16 b = __float2bfloat16(v);
    return *(ushort*)&b;
}
__device__ __forceinline__ float bs2f(ushort u) {
    __hip_bfloat16 b = *(__hip_bfloat16*)&u;
    return __bfloat162float(b);
}
// tiled plane addr, K-extent 256 (h planes): 16x32 fragment tiles of 512 halves
__device__ __forceinline__ size_t taddrH(int n, int k) {
    return (size_t)(n >> 4) * 4096 + (size_t)((k >> 5) << 9)
         + (size_t)(((k >> 3) & 3) << 7) + (size_t)((n & 15) << 3) + (k & 7);
}
// tiled plane addr, K-extent 512 (agg hi|lo combined)
__device__ __forceinline__ size_t taddrA(int n, int k) {
    return (size_t)(n >> 4) * 8192 + (size_t)((k >> 5) << 9)
         + (size_t)(((k >> 3) & 3) << 7) + (size_t)((n & 15) << 3) + (k & 7);
}

// flags[0] = 1 if float tensors are bf16, 0 if f32
// flags[1] = 1 if edge_index is int64, 0 if int32
__global__ void detect_k(const void* x, const void* ei, int* flags) {
    if (blockIdx.x == 0 && threadIdx.x == 0) {
        const __hip_bfloat16* xb = (const __hip_bfloat16*)x;
        int isbf = 1;
        for (int i = 0; i < 1024; ++i) {
            float v = fabsf(__bfloat162float(xb[i]));
            if (!(v < 1e6f)) { isbf = 0; break; }
        }
        flags[0] = isbf;
        const int* e32 = (const int*)ei;
        int orv = e32[1] | e32[3] | e32[5] | e32[7] | e32[9] | e32[11];
        flags[1] = (orv == 0) ? 1 : 0;
    }
}

// x -> h planes (tiled); pad rows zeroed
__global__ void conv_h0_k(const void* x, ushort* HH, ushort* HL,
                          const int* flags, int useHL, int Nn, size_t npad256) {
    size_t i = (size_t)blockIdx.x * blockDim.x + threadIdx.x;
    if (i >= npad256) return;
    const int n = (int)(i >> 8), k = (int)(i & 255);
    float v = 0.f;
    if (n < Nn) v = ldf(x, i, flags[0]);
    const ushort hi = f2bs(v);
    const size_t a = taddrH(n, k);
    HH[a] = hi;
    if (useHL) HL[a] = f2bs(v - bs2f(hi));
}

// Build tiled B matrices + biases.
// Bg [1024 out][1024 k] logical; out col j: q=j>>6, gate g=(j>>4)&3, b=16q+(j&15).
//   k seg 0/1 (agg hi/lo): g in {r,z,ni}: Wih[g*256+b][kk]; nh: 0
//   k seg 2/3 (h hi/lo):   g in {r,z}: Whh[...]; nh: Whh[512+b][kk]; ni: 0
// Bw [L][256 out][512 k]: Wt (both h hi/lo segs).
__global__ void prep_k(const void* w, const void* wih, const void* whh,
                       const void* bih, const void* bhh,
                       ushort* BgH, ushort* BgL, ushort* BwH, ushort* BwL,
                       float* bsum, float* bni, float* bnh,
                       const int* flags, int L) {
    int i = blockIdx.x * blockDim.x + threadIdx.x;
    int isbf = flags[0];
    if (i < 1048576) {
        const int j = i >> 10, k = i & 1023;
        const int g = (j >> 4) & 3, b = ((j >> 6) << 4) + (j & 15);
        const int kk = k & 255, seg = k >> 8;
        float v = 0.f;
        if (g == 0) v = (seg < 2) ? ldf(wih, (size_t)b * 256 + kk, isbf)
                                  : ldf(whh, (size_t)b * 256 + kk, isbf);
        else if (g == 1) v = (seg < 2) ? ldf(wih, (size_t)(256 + b) * 256 + kk, isbf)
                                       : ldf(whh, (size_t)(256 + b) * 256 + kk, isbf);
        else if (g == 2) v = (seg < 2) ? ldf(wih, (size_t)(512 + b) * 256 + kk, isbf) : 0.f;
        else             v = (seg < 2) ? 0.f : ldf(whh, (size_t)(512 + b) * 256 + kk, isbf);
        const ushort hi = f2bs(v);
        const int ct = j >> 4, c = k >> 5;
        const size_t a = (size_t)(ct * 32 + c) * 512
                       + (size_t)(((k >> 3) & 3) << 7) + ((j & 15) << 3) + (k & 7);
        BgH[a] = hi; BgL[a] = f2bs(v - bs2f(hi));
    }
    if (i < L * 131072) {
        const int l = i >> 17, r2 = i & 131071;
        const int j = r2 >> 9, k = r2 & 511;
        const int kk = k & 255;
        const float v = ldf(w, ((size_t)l << 16) + (size_t)kk * 256 + j, isbf);
        const ushort hi = f2bs(v);
        const int ct = j >> 4, c = k >> 5;
        const size_t a = (size_t)l * 131072 + (size_t)(ct * 16 + c) * 512
                       + (size_t)(((k >> 3) & 3) << 7) + ((j & 15) << 3) + (k & 7);
        BwH[a] = hi; BwL[a] = f2bs(v - bs2f(hi));
    }
    if (i < 512) bsum[i] = ldf(bih, i, isbf) + ldf(bhh, i, isbf);
    if (i < 256) {
        bni[i] = ldf(bih, 512 + i, isbf);
        bnh[i] = ldf(bhh, 512 + i, isbf);
    }
}

// ---------------- CSR build (by dst), once per call ----------------

__global__ void zero_int_k(int* p, int n) {
    int i = blockIdx.x * blockDim.x + threadIdx.x;
    if (i < n) p[i] = 0;
}

__global__ void count_k(const void* ei, int* cnt, const int* flags, int E) {
    int e = blockIdx.x * blockDim.x + threadIdx.x;
    if (e >= E) return;
    const int* e32 = (const int*)ei;
    int d = flags[1] ? e32[2 * ((size_t)E + e)] : e32[(size_t)E + e];
    atomicAdd(&cnt[d], 1);
}

__global__ __launch_bounds__(256)
void scan1_k(const int* cnt, int* ptr, int* bsumN, int N) {
    __shared__ int s[256];
    const int t = threadIdx.x;
    const int gid = blockIdx.x * 256 + t;
    int v = (gid < N) ? cnt[gid] : 0;
    const int own = v;
    s[t] = v;
    __syncthreads();
#pragma unroll
    for (int off = 1; off < 256; off <<= 1) {
        int add = (t >= off) ? s[t - off] : 0;
        __syncthreads();
        s[t] += add;
        __syncthreads();
    }
    if (gid < N) ptr[gid] = s[t] - own;
    if (t == 255) bsumN[blockIdx.x] = s[255];
}

__global__ __launch_bounds__(256)
void scan2_k(int* bsumN, int NB) {
    __shared__ int s[256];
    __shared__ int carry;
    const int t = threadIdx.x;
    if (t == 0) carry = 0;
    __syncthreads();
    for (int base = 0; base < NB; base += 256) {
        const int i = base + t;
        int v = (i < NB) ? bsumN[i] : 0;
        const int own = v;
        s[t] = v;
        __syncthreads();
#pragma unroll
        for (int off = 1; off < 256; off <<= 1) {
            int add = (t >= off) ? s[t - off] : 0;
            __syncthreads();
            s[t] += add;
            __syncthreads();
        }
        if (i < NB) bsumN[i] = carry + s[t] - own;
        __syncthreads();
        if (t == 0) carry += s[255];
        __syncthreads();
    }
}

__global__ void scan3_k(int* ptr, int* cursor, const int* bsumN, int N, int E) {
    const int gid = blockIdx.x * 256 + threadIdx.x;
    if (gid < N) {
        const int p = ptr[gid] + bsumN[blockIdx.x];
        ptr[gid] = p;
        cursor[gid] = p;
    }
    if (gid == 0) ptr[N] = E;
}

__global__ void fill_k(const void* ei, const void* ew, int* cursor,
                       int* srcs, float* wse, const int* flags, int E) {
    int e = blockIdx.x * blockDim.x + threadIdx.x;
    if (e >= E) return;
    const int* e32 = (const int*)ei;
    int s, d;
    if (flags[1]) { s = e32[2 * (size_t)e]; d = e32[2 * ((size_t)E + e)]; }
    else          { s = e32[e];             d = e32[(size_t)E + e]; }
    const int p = atomicAdd(&cursor[d], 1);
    srcs[p] = s;
    wse[p] = ldf(ew, e, flags[0]);
}

// ---------------- SpMM gather: agg[d] = sum_j w_j * m[src_j] ----------------
// Writes AGG combined plane (hi at k, lo at 256+k), tiled layout.
__global__ __launch_bounds__(256)
void spmm_k(const float* __restrict__ m, const int* __restrict__ ptr,
            const int* __restrict__ srcs, const float* __restrict__ wse,
            ushort* __restrict__ AGG, int N) {
    const int node = blockIdx.x * 4 + (threadIdx.x >> 6);
    if (node >= N) return;
    const int lane4 = (threadIdx.x & 63) << 2;
    const int p0 = ptr[node], p1 = ptr[node + 1];
    float4 acc = make_float4(0.f, 0.f, 0.f, 0.f);
    int j = p0;
    for (; j + 1 < p1; j += 2) {
        const int s0 = srcs[j], s1 = srcs[j + 1];
        const float w0 = wse[j], w1 = wse[j + 1];
        const float4 v0 = *(const float4*)&m[(size_t)s0 * HDIM + lane4];
        const float4 v1 = *(const float4*)&m[(size_t)s1 * HDIM + lane4];
        acc.x = fmaf(w0, v0.x, acc.x); acc.y = fmaf(w0, v0.y, acc.y);
        acc.z = fmaf(w0, v0.z, acc.z); acc.w = fmaf(w0, v0.w, acc.w);
        acc.x = fmaf(w1, v1.x, acc.x); acc.y = fmaf(w1, v1.y, acc.y);
        acc.z = fmaf(w1, v1.z, acc.z); acc.w = fmaf(w1, v1.w, acc.w);
    }
    if (j < p1) {
        const int s0 = srcs[j];
        const float w0 = wse[j];
        const float4 v0 = *(const float4*)&m[(size_t)s0 * HDIM + lane4];
        acc.x = fmaf(w0, v0.x, acc.x); acc.y = fmaf(w0, v0.y, acc.y);
        acc.z = fmaf(w0, v0.z, acc.z); acc.w = fmaf(w0, v0.w, acc.w);
    }
    ushort4 hi, lo;
    hi.x = f2bs(acc.x); lo.x = f2bs(acc.x - bs2f(hi.x));
    hi.y = f2bs(acc.y); lo.y = f2bs(acc.y - bs2f(hi.y));
    hi.z = f2bs(acc.z); lo.z = f2bs(acc.z - bs2f(hi.z));
    hi.w = f2bs(acc.w); lo.w = f2bs(acc.w - bs2f(hi.w));
    *(ushort4*)&AGG[taddrA(node, lane4)] = hi;
    *(ushort4*)&AGG[taddrA(node, 256 + lane4)] = lo;
}

// ---------------- m97-style GEMM #1: m = h @ Wt^T ---------------------------
// 128x128 tile, 4 waves (2x2 quadrants), 4x4 16x16-tiles per wave (64 acc
// f32/thread). BK=32; A+B tiles glds-staged (1KB contiguous per glds);
// 2 barriers/chunk; fragments via conflict-free ds_read_b128.
__global__ __launch_bounds__(256)
void m_gemm_k(const ushort* __restrict__ HH, const ushort* __restrict__ HL,
              const ushort* __restrict__ BwHl, const ushort* __restrict__ BwLl,
              float* __restrict__ m, const int* __restrict__ flags,
              int useHL, int nRB) {
    __shared__ ushort lds[12288];  // A 4096 | Bh 4096 | Bl 4096 halves (24KB)
    const int rb = blockIdx.x >> 1, cgB = blockIdx.x & 1;
    if (rb >= nRB) return;
    const int tid = threadIdx.x, lane = tid & 63;
    const int wv = __builtin_amdgcn_readfirstlane(tid >> 6);
    const int wr = wv & 1, wc = wv >> 1;
    const int lm = lane & 15, lq = lane >> 4;
    const int fullsplit = !flags[0];
    const int NCH = useHL ? 16 : 8;
    const int rt = rb * 8, t0 = 2 * wv;
    f32x4 acc[4][4];
#pragma unroll
    for (int i = 0; i < 4; ++i)
#pragma unroll
        for (int j = 0; j < 4; ++j) acc[i][j] = (f32x4){0.f, 0.f, 0.f, 0.f};

    for (int c = 0; c < NCH; ++c) {
        __syncthreads();
        const ushort* a0 = (c < 8)
            ? HH + (size_t)(rt + t0) * 4096 + (size_t)c * 512
            : HL + (size_t)(rt + t0) * 4096 + (size_t)(c - 8) * 512;
        GLD16(a0 + (size_t)lane * 8, &lds[t0 * 512]);
        GLD16(a0 + 4096 + (size_t)lane * 8, &lds[t0 * 512 + 512]);
        const size_t bb = ((size_t)(8 * cgB + t0) * 16 + c) * 512;
        GLD16(BwHl + bb + (size_t)lane * 8, &lds[4096 + t0 * 512]);
        GLD16(BwHl + bb + 8192 + (size_t)lane * 8, &lds[4096 + t0 * 512 + 512]);
        if (fullsplit) {
            GLD16(BwLl + bb + (size_t)lane * 8, &lds[8192 + t0 * 512]);
            GLD16(BwLl + bb + 8192 + (size_t)lane * 8, &lds[8192 + t0 * 512 + 512]);
        }
        __syncthreads();
        bf16x8 af[4], bf[4];
#pragma unroll
        for (int i = 0; i < 4; ++i)
            af[i] = ldfrag(&lds[(4 * wr + i) * 512 + lq * 128 + lm * 8]);
#pragma unroll
        for (int j = 0; j < 4; ++j)
            bf[j] = ldfrag(&lds[4096 + (4 * wc + j) * 512 + lq * 128 + lm * 8]);
#pragma unroll
        for (int i = 0; i < 4; ++i)
#pragma unroll
            for (int j = 0; j < 4; ++j) acc[i][j] = MFMA(af[i], bf[j], acc[i][j]);
        if (fullsplit) {
#pragma unroll
            for (int j = 0; j < 4; ++j) {
                const bf16x8 bl = ldfrag(&lds[8192 + (4 * wc + j) * 512 + lq * 128 + lm * 8]);
#pragma unroll
                for (int i = 0; i < 4; ++i) acc[i][j] = MFMA(af[i], bl, acc[i][j]);
            }
        }
    }
#pragma unroll
    for (int i = 0; i < 4; ++i) {
        const int row = rb * 128 + wr * 64 + i * 16 + lq * 4;
#pragma unroll
        for (int j = 0; j < 4; ++j) {
            const int col = cgB * 128 + wc * 64 + j * 16 + lm;
#pragma unroll
            for (int v = 0; v < 4; ++v)
                m[(size_t)(row + v) * 256 + col] = acc[i][j][v];  // m is padded
        }
    }
}

// ---------------- m97-style GEMM #2: gates + fused GRU ----------------------
// A = [AGG(k 0..511) | hH(512..767) | hL(768..1023)], B = Bg (permuted).
// Wave's 4 col-tiles = (r,z,ni,nh) for 16 hidden units -> local GRU epilogue.
// Swizzle: bid = x + 8*cgB + 64*rbHi with rb = rbHi*8+x -> 8 col-peers share
// bid%8 (same XCD candidate) and a 64-bid window.
__global__ __launch_bounds__(256)
void gates_k(const ushort* __restrict__ AGG,
             const ushort* __restrict__ HH, const ushort* __restrict__ HL,
             const ushort* __restrict__ BgH, const ushort* __restrict__ BgL,
             const float* __restrict__ bsum, const float* __restrict__ bni,
             const float* __restrict__ bnh,
             ushort* __restrict__ HnH, ushort* __restrict__ HnL,
             const int* __restrict__ flags, int useHL, int nRB) {
    __shared__ ushort lds[12288];
    const int x = blockIdx.x & 7, rem = blockIdx.x >> 3;
    const int cgB = rem & 7, rbHi = rem >> 3;
    const int rb = rbHi * 8 + x;
    if (rb >= nRB) return;
    const int tid = threadIdx.x, lane = tid & 63;
    const int wv = __builtin_amdgcn_readfirstlane(tid >> 6);
    const int wr = wv & 1, wc = wv >> 1;
    const int lm = lane & 15, lq = lane >> 4;
    const int fullsplit = !flags[0];
    const int NCH = useHL ? 32 : 24;
    const int rt = rb * 8, t0 = 2 * wv;
    f32x4 acc[4][4];
#pragma unroll
    for (int i = 0; i < 4; ++i)
#pragma unroll
        for (int j = 0; j < 4; ++j) acc[i][j] = (f32x4){0.f, 0.f, 0.f, 0.f};

    for (int c = 0; c < NCH; ++c) {
        __syncthreads();
        const ushort* a0;
        size_t stride;
        if (c < 16)      { a0 = AGG + (size_t)(rt + t0) * 8192 + (size_t)c * 512; stride = 8192; }
        else if (c < 24) { a0 = HH + (size_t)(rt + t0) * 4096 + (size_t)(c - 16) * 512; stride = 4096; }
        else             { a0 = HL + (size_t)(rt + t0) * 4096 + (size_t)(c - 24) * 512; stride = 4096; }
        GLD16(a0 + (size_t)lane * 8, &lds[t0 * 512]);
        GLD16(a0 + stride + (size_t)lane * 8, &lds[t0 * 512 + 512]);
        const size_t bb = ((size_t)(8 * cgB + t0) * 32 + c) * 512;
        GLD16(BgH + bb + (size_t)lane * 8, &lds[4096 + t0 * 512]);
        GLD16(BgH + bb + 16384 + (size_t)lane * 8, &lds[4096 + t0 * 512 + 512]);
        if (fullsplit) {
            GLD16(BgL + bb + (size_t)lane * 8, &lds[8192 + t0 * 512]);
            GLD16(BgL + bb + 16384 + (size_t)lane * 8, &lds[8192 + t0 * 512 + 512]);
        }
        __syncthreads();
        bf16x8 af[4], bf[4];
#pragma unroll
        for (int i = 0; i < 4; ++i)
            af[i] = ldfrag(&lds[(4 * wr + i) * 512 + lq * 128 + lm * 8]);
#pragma unroll
        for (int j = 0; j < 4; ++j)
            bf[j] = ldfrag(&lds[4096 + (4 * wc + j) * 512 + lq * 128 + lm * 8]);
#pragma unroll
        for (int i = 0; i < 4; ++i)
#pragma unroll
            for (int j = 0; j < 4; ++j) acc[i][j] = MFMA(af[i], bf[j], acc[i][j]);
        if (fullsplit) {
#pragma unroll
            for (int j = 0; j < 4; ++j) {
                const bf16x8 bl = ldfrag(&lds[8192 + (4 * wc + j) * 512 + lq * 128 + lm * 8]);
#pragma unroll
                for (int i = 0; i < 4; ++i) acc[i][j] = MFMA(af[i], bl, acc[i][j]);
            }
        }
    }
    // GRU epilogue: col-tile 0..3 = r,z,ni,nh for hidden unit b
    const int b = (2 * cgB + wc) * 16 + lm;
    const float rbias = bsum[b], zbias = bsum[256 + b];
    const float ibias = bni[b], hbias = bnh[b];
#pragma unroll
    for (int i = 0; i < 4; ++i) {
        const int row0 = rb * 128 + wr * 64 + i * 16 + lq * 4;
#pragma unroll
        for (int v = 0; v < 4; ++v) {
            const int row = row0 + v;
            const size_t ho = taddrH(row, b);  // buffers padded; pads benign
            float hold = bs2f(HH[ho]);
            if (useHL) hold += bs2f(HL[ho]);
            const float r = 1.f / (1.f + expf(-(acc[i][0][v] + rbias)));
            const float z = 1.f / (1.f + expf(-(acc[i][1][v] + zbias)));
            const float nn = tanhf(acc[i][2][v] + ibias + r * (acc[i][3][v] + hbias));
            const float hv = (1.f - z) * nn + z * hold;
            const ushort hi = f2bs(hv);
            HnH[ho] = hi;
            if (useHL) HnL[ho] = f2bs(hv - bs2f(hi));
        }
    }
}

// out[n] = sum_t relu(h[n,t]) * fc_w[t] + fc_b ; one 256-thread block per node
__global__ void final_k(const ushort* __restrict__ HH, const ushort* __restrict__ HL,
                        const void* fcw, const void* fcb,
                        void* out, const int* flags, int useHL, int N) {
    const int n = blockIdx.x;
    const int t = threadIdx.x;
    const int isbf = flags[0];
    const size_t off = taddrH(n, t);
    float h = bs2f(HH[off]);
    if (useHL) h += bs2f(HL[off]);
    float v = fmaxf(h, 0.f) * ldf(fcw, t, isbf);
#pragma unroll
    for (int offx = 32; offx >= 1; offx >>= 1) v += __shfl_down(v, offx);
    __shared__ float red[4];
    if ((t & 63) == 0) red[t >> 6] = v;
    __syncthreads();
    if (t == 0) {
        const float s = red[0] + red[1] + red[2] + red[3] + ldf(fcb, 0, isbf);
        if (isbf) ((__hip_bfloat16*)out)[n] = __float2bfloat16(s);
        else      ((float*)out)[n] = s;
    }
}

extern "C" void kernel_launch(void* const* d_in, const int* in_sizes, int n_in,
                              void* d_out, int out_size, void* d_ws, size_t ws_size,
                              hipStream_t stream) {
    const int H = HDIM;
    const int N = in_sizes[0] / H;       // 50000
    const int E = in_sizes[2];           // 800000
    const int L = in_sizes[3] / (H * H); // 5
    const int NB = (N + 255) / 256;
    const int nRB = (N + 127) / 128;     // 391
    const size_t NPAD = (size_t)nRB * 128;
    const size_t hHalf = NPAD * 256;     // halves per h plane
    const size_t aggHalf = NPAD * 512;

    char* p = (char*)d_ws;
    int*    flags = (int*)p;              p += 64;
    ushort* AGG  = (ushort*)p;            p += aggHalf * 2;
    ushort* HxH  = (ushort*)p;            p += hHalf * 2;
    ushort* HyH  = (ushort*)p;            p += hHalf * 2;
    float*  m    = (float*)p;             p += NPAD * 256 * 4;
    ushort* BgH  = (ushort*)p;            p += (size_t)1048576 * 2;
    ushort* BgL  = (ushort*)p;            p += (size_t)1048576 * 2;
    ushort* BwH  = (ushort*)p;            p += (size_t)L * 131072 * 2;
    ushort* BwL  = (ushort*)p;            p += (size_t)L * 131072 * 2;
    float*  bsum = (float*)p;             p += 512 * 4;
    float*  bni  = (float*)p;             p += 256 * 4;
    float*  bnh  = (float*)p;             p += 256 * 4;
    int*    ptr  = (int*)p;               p += (size_t)(N + 1) * 4;
    int*    cursor = (int*)p;             p += (size_t)N * 4;
    int*    bsumN  = (int*)p;             p += (size_t)NB * 4;
    int*    srcs   = (int*)p;             p += (size_t)E * 4;
    float*  wse    = (float*)p;           p += (size_t)E * 4;
    const size_t need_reduced = (size_t)(p - (char*)d_ws);
    ushort* HxL = (ushort*)p;             // optional hi/lo h planes
    ushort* HyL = (ushort*)(p + hHalf * 2);
    const size_t need_full = need_reduced + 2 * hHalf * 2;
    const int useHL = (ws_size >= need_full) ? 1 : 0;
    if (!useHL) { HxL = HxH; HyL = HyH; }  // never dereferenced when useHL=0

    detect_k<<<dim3(1), dim3(64), 0, stream>>>(d_in[0], d_in[1], flags);
    conv_h0_k<<<dim3((unsigned)NPAD), dim3(256), 0, stream>>>(
        d_in[0], HxH, HxL, flags, useHL, N, NPAD * 256);
    prep_k<<<dim3(4096), dim3(256), 0, stream>>>(
        d_in[3], d_in[4], d_in[5], d_in[6], d_in[7],
        BgH, BgL, BwH, BwL, bsum, bni, bnh, flags, L);

    zero_int_k<<<dim3(NB), dim3(256), 0, stream>>>(cursor, N);
    count_k<<<dim3((E + 255) / 256), dim3(256), 0, stream>>>(d_in[1], cursor, flags, E);
    scan1_k<<<dim3(NB), dim3(256), 0, stream>>>(cursor, ptr, bsumN, N);
    scan2_k<<<dim3(1), dim3(256), 0, stream>>>(bsumN, NB);
    scan3_k<<<dim3(NB), dim3(256), 0, stream>>>(ptr, cursor, bsumN, N, E);
    fill_k<<<dim3((E + 255) / 256), dim3(256), 0, stream>>>(
        d_in[1], d_in[2], cursor, srcs, wse, flags, E);

    const dim3 blk(256);
    const unsigned gGrid = 64u * (unsigned)((nRB + 7) / 8);
    ushort *HcH = HxH, *HcL = HxL, *HnH = HyH, *HnL = HyL;
    for (int l = 0; l < L; ++l) {
        m_gemm_k<<<dim3((unsigned)(2 * nRB)), blk, 0, stream>>>(
            HcH, HcL, BwH + (size_t)l * 131072, BwL + (size_t)l * 131072,
            m, flags, useHL, nRB);
        spmm_k<<<dim3((N + 3) / 4), blk, 0, stream>>>(m, ptr, srcs, wse, AGG, N);
        gates_k<<<dim3(gGrid), blk, 0, stream>>>(
            AGG, HcH, HcL, BgH, BgL, bsum, bni, bnh, HnH, HnL, flags, useHL, nRB);
        ushort* t;
        t = HcH; HcH = HnH; HnH = t;
        t = HcL; HcL = HnL; HnL = t;
    }
    final_k<<<dim3(N), blk, 0, stream>>>(
        HcH, HcL, d_in[8], d_in[9], d_out, flags, useHL, N);
}